// Round 6
// baseline (241.965 us; speedup 1.0000x reference)
//
#include <hip/hip_runtime.h>

// VQ-VAE forward + EMA update, MI355X.
// Sizes fixed by the reference: B=64, C=D=8, H=W=64, K=512.
constexpr int Kc   = 512;
constexpr int Dc   = 8;
constexpr int HWc  = 4096;            // 64*64
constexpr int CHWc = Dc * HWc;        // 32768
constexpr int Mc   = 64 * HWc;        // 262144 vectors
constexpr int TOTALc = Mc * Dc;       // 2097152 elements of z / z_q

// 8 replica accumulators (one per XCD via blockIdx&7) to cut atomic contention.
constexpr int REP      = 8;
constexpr int RSTRIDE  = 4616;        // 512 counts + 4096 sums + 1 loss + 7 pad
constexpr int ACC_FLOATS = REP * RSTRIDE;   // 36928 floats (~148 KB)
// d_ws float layout:
//   [0 .. ACC_FLOATS)            replica accumulators (counts | sums | loss | pad) x8
//   [ACC_FLOATS .. +512)         e_sq[k]
//   [ACC_FLOATS + 512]           ticket (uint) for last-block-does-final

typedef float v2f __attribute__((ext_vector_type(2)));

__global__ __launch_bounds__(256) void vq_prep(const float* __restrict__ cb,
                                               float* __restrict__ ws) {
    const int tid = blockIdx.x * 256 + threadIdx.x;
    float4* w4 = (float4*)ws;
    for (int i = tid; i < ACC_FLOATS / 4; i += gridDim.x * 256)
        w4[i] = float4{0.f, 0.f, 0.f, 0.f};
    if (blockIdx.x == 0) {
        for (int k = threadIdx.x; k < Kc; k += 256) {
            float s = 0.f;
#pragma unroll
            for (int c = 0; c < Dc; ++c) {
                const float e = cb[k * Dc + c];
                s = fmaf(e, e, s);
            }
            ws[ACC_FLOATS + k] = s;
        }
        if (threadIdx.x == 0)
            ((unsigned*)ws)[ACC_FLOATS + 512] = 0u;   // ticket
    }
}

// 1024 blocks x 512 threads; block owns 256 consecutive vectors.
// 8 k-groups x 1 wave (unique codes per wave); lane l scores V=4 vectors
// (l, l+64, l+128, l+192) via v_pk_fma_f32 with the codebook c-pair in an
// SGPR pair, broadcast lo/hi via op_sel. Math BIT-IDENTICAL to the 47us
// baseline: a = esq[k]; a += zz[c]*e[c], c ascending; strict-< first-wins.
// NEW vs r4: (a) accumulator init folded into the first pk_fma (addend
// {ev,ev} — 2 movs/code instead of 4); (b) unroll 4 (deeper s_load batches,
// esq quad merges into s_load_dwordx4); (c) vq_final FUSED here via a
// device-scope ticket — the 1024th block to finish runs the final phase.
__global__ __launch_bounds__(512, 8) void vq_main(const float* __restrict__ z,
                                                  const float* __restrict__ cb,
                                                  const float* __restrict__ esq,
                                                  float* __restrict__ ws,
                                                  float* __restrict__ zq,
                                                  const float* __restrict__ ema_cs,
                                                  const float* __restrict__ ema_w,
                                                  float* __restrict__ out) {
    __shared__ float s_mn[8][256];         // 8 KB   (reused as s_cs in final)
    __shared__ int   s_im[8][256];         // 8 KB
    __shared__ float s_counts[Kc];         // 2 KB   (reused as red in final)
    __shared__ float s_sums[Kc * Dc];      // 16 KB
    __shared__ float s_loss;
    __shared__ unsigned s_tick;

    const int t = threadIdx.x;
    for (int i = t; i < Kc; i += 512) s_counts[i] = 0.f;
    for (int i = t; i < Kc * Dc; i += 512) s_sums[i] = 0.f;
    if (t == 0) s_loss = 0.f;

    const int l = t & 63;
    // wave-uniform k-group; readfirstlane keeps codebook indices provably
    // uniform -> s_load (scalar) path for cb/esq.
    const int g  = __builtin_amdgcn_readfirstlane(t >> 6);   // 0..7
    const int k0 = g << 6;

    const int base = blockIdx.x * 256;        // 256-aligned -> one batch idx
    const int b  = base >> 12;
    const int n0 = (base & (HWc - 1)) + l;    // +64*j below never wraps 4096
    const float* zb = z + b * CHWc + n0;

    // zzA[c] = (-2*z[vec l][c], -2*z[vec l+64][c]); zzB: vecs l+128, l+192.
    v2f zzA[Dc], zzB[Dc];
#pragma unroll
    for (int c = 0; c < Dc; ++c) {
        zzA[c] = v2f{-2.0f * zb[c * HWc],       -2.0f * zb[c * HWc + 64]};
        zzB[c] = v2f{-2.0f * zb[c * HWc + 128], -2.0f * zb[c * HWc + 192]};
    }

    const unsigned long long* cbq = (const unsigned long long*)cb; // 4 qw/row

    float mn0 = 3.4e38f, mn1 = 3.4e38f, mn2 = 3.4e38f, mn3 = 3.4e38f;
    int   i0 = k0, i1 = k0, i2 = k0, i3 = k0;
#pragma unroll 4
    for (int kk = 0; kk < 64; ++kk) {
        const int k = k0 + kk;
        const unsigned long long q0 = cbq[4 * k + 0];  // (e0,e1) uniform
        const unsigned long long q1 = cbq[4 * k + 1];  // (e2,e3)
        const unsigned long long q2 = cbq[4 * k + 2];  // (e4,e5)
        const unsigned long long q3 = cbq[4 * k + 3];  // (e6,e7)
        const float ev = esq[k];                       // uniform -> s_load
        const v2f vev2 = {ev, ev};
        v2f aA, aB;
        // op_sel_hi:[1,0,1] broadcasts the LOW dword of the sgpr pair
        // (e[2p]); op_sel:[0,1,0] (default op_sel_hi) broadcasts the HIGH
        // dword (e[2p+1]). First step folds the {ev,ev} addend directly
        // (same value & rounding as init-then-fma). Chain: c ascending.
        asm("v_pk_fma_f32 %0, %2, %4, %5 op_sel_hi:[1,0,1]\n\t"
            "v_pk_fma_f32 %1, %3, %4, %5 op_sel_hi:[1,0,1]\n\t"
            "v_pk_fma_f32 %0, %6, %4, %0 op_sel:[0,1,0]\n\t"
            "v_pk_fma_f32 %1, %7, %4, %1 op_sel:[0,1,0]"
            : "=&v"(aA), "=&v"(aB)
            : "v"(zzA[0]), "v"(zzB[0]), "s"(q0), "v"(vev2),
              "v"(zzA[1]), "v"(zzB[1]));
#define PKSTEP(Q, P0, P1)                                              \
        asm("v_pk_fma_f32 %0, %2, %4, %0 op_sel_hi:[1,0,1]\n\t"        \
            "v_pk_fma_f32 %1, %3, %4, %1 op_sel_hi:[1,0,1]\n\t"        \
            "v_pk_fma_f32 %0, %5, %4, %0 op_sel:[0,1,0]\n\t"           \
            "v_pk_fma_f32 %1, %6, %4, %1 op_sel:[0,1,0]"               \
            : "+v"(aA), "+v"(aB)                                       \
            : "v"(zzA[P0]), "v"(zzB[P0]), "s"(Q), "v"(zzA[P1]), "v"(zzB[P1]))
        PKSTEP(q1, 2, 3);
        PKSTEP(q2, 4, 5);
        PKSTEP(q3, 6, 7);
#undef PKSTEP
        const float a0 = aA.x, a1 = aA.y, a2 = aB.x, a3 = aB.y;
        bool c;
        c = a0 < mn0; mn0 = c ? a0 : mn0; i0 = c ? k : i0;
        c = a1 < mn1; mn1 = c ? a1 : mn1; i1 = c ? k : i1;
        c = a2 < mn2; mn2 = c ? a2 : mn2; i2 = c ? k : i2;
        c = a3 < mn3; mn3 = c ? a3 : mn3; i3 = c ? k : i3;
    }
    s_mn[g][l]       = mn0;  s_im[g][l]       = i0;
    s_mn[g][l +  64] = mn1;  s_im[g][l +  64] = i1;
    s_mn[g][l + 128] = mn2;  s_im[g][l + 128] = i2;
    s_mn[g][l + 192] = mn3;  s_im[g][l + 192] = i3;
    __syncthreads();

    if (t < 256) {
        const int v = t;                      // block-local vector id
        float mn = s_mn[0][v];
        int   im = s_im[0][v];
#pragma unroll
        for (int gg = 1; gg < 8; ++gg) {
            const float m2 = s_mn[gg][v];     // groups ascending in k:
            const int   j2 = s_im[gg][v];     // strict < keeps first index
            const bool  c2 = m2 < mn;
            mn = c2 ? m2 : mn;
            im = c2 ? j2 : im;
        }

        // Gather old-codebook row (16 KB table, L1-hot; 32B/lane).
        const float4* cb4 = (const float4*)cb;
        const float4 qa = cb4[im * 2], qb = cb4[im * 2 + 1];
        const float q[Dc] = {qa.x, qa.y, qa.z, qa.w, qb.x, qb.y, qb.z, qb.w};

        const int nv = (base & (HWc - 1)) + v;
        const float* zv = z + b * CHWc + nv;  // re-read z (L1/L2-hot)
        float* zqv = zq + b * CHWc + nv;
        float lsum = 0.f;
        float zr[Dc];
#pragma unroll
        for (int c = 0; c < Dc; ++c) {
            zr[c] = zv[c * HWc];
            zqv[c * HWc] = q[c];              // coalesced stores
            const float d = q[c] - zr[c];
            lsum = fmaf(d, d, lsum);
        }

        // Per-block LDS histogram (ds_add_f32) — coalesces same-index hits.
        unsafeAtomicAdd(&s_counts[im], 1.0f);
#pragma unroll
        for (int c = 0; c < Dc; ++c)
            unsafeAtomicAdd(&s_sums[im * Dc + c], zr[c]);
        unsafeAtomicAdd(&s_loss, lsum);
    }
    __syncthreads();

    // Flush non-zero bins to this block's replica accumulator (all 512 thr).
    float* acc = ws + (blockIdx.x & (REP - 1)) * RSTRIDE;
    for (int i = t; i < Kc; i += 512) {
        const float val = s_counts[i];
        if (val != 0.f) unsafeAtomicAdd(&acc[i], val);
    }
    for (int i = t; i < Kc * Dc; i += 512) {
        const float val = s_sums[i];
        if (val != 0.f) unsafeAtomicAdd(&acc[512 + i], val);
    }
    if (t == 0) unsafeAtomicAdd(&acc[4608], s_loss);

    // ---- fused final: last block to arrive does the EMA/codebook update ----
    __threadfence();                          // release my flush atomics
    __syncthreads();
    if (t == 0)
        s_tick = __hip_atomic_fetch_add((unsigned*)(ws + ACC_FLOATS + 512), 1u,
                                        __ATOMIC_ACQ_REL,
                                        __HIP_MEMORY_SCOPE_AGENT);
    __syncthreads();                          // s_tick uniform across block
    if (s_tick == 1023u) {
        __threadfence();                      // acquire side (conservative)
        constexpr float DEC  = 0.99f;
        constexpr float OMD  = (float)(1.0 - 0.99);  // matches jnp f32 cast
        constexpr float EPSf = 1e-5f;
        constexpr float KEPS = (float)(512 * 1e-5);  // 0.00512
        float* red = s_counts;                // reuse LDS
        float* scs = &s_mn[0][0];

        float cnt = 0.f;
#pragma unroll
        for (int r = 0; r < REP; ++r) cnt += ws[r * RSTRIDE + t];
        const float ncs = ema_cs[t] * DEC + cnt * OMD;
        red[t] = ncs;
        __syncthreads();
        for (int s = 256; s > 0; s >>= 1) {
            if (t < s) red[t] += red[t + s];
            __syncthreads();
        }
        const float n  = red[0];
        const float cs = (ncs + EPSf) / (n + KEPS) * n;
        scs[t] = cs;

        float* out_loss = out + TOTALc;          // [1]
        float* out_cb   = out + TOTALc + 1;      // [K*D]
        float* out_cs   = out_cb + Kc * Dc;      // [K]
        float* out_nw   = out_cs + Kc;           // [K*D]

        out_cs[t] = cs;
        __syncthreads();

        for (int e = t; e < Kc * Dc; e += 512) {
            float sm = 0.f;
#pragma unroll
            for (int r = 0; r < REP; ++r) sm += ws[r * RSTRIDE + 512 + e];
            const float nw = ema_w[e] * DEC + sm * OMD;
            out_nw[e] = nw;
            out_cb[e] = nw / scs[e >> 3];
        }
        if (t == 0) {
            float ls = 0.f;
#pragma unroll
            for (int r = 0; r < REP; ++r) ls += ws[r * RSTRIDE + 4608];
            out_loss[0] = ls * (1.0f / 2097152.0f);  // /2^21 exact
        }
    }
}

extern "C" void kernel_launch(void* const* d_in, const int* in_sizes, int n_in,
                              void* d_out, int out_size, void* d_ws, size_t ws_size,
                              hipStream_t stream) {
    const float* z      = (const float*)d_in[0];
    const float* cb     = (const float*)d_in[1];
    const float* ema_cs = (const float*)d_in[2];
    const float* ema_w  = (const float*)d_in[3];
    float* out = (float*)d_out;
    float* ws  = (float*)d_ws;

    vq_prep<<<32, 256, 0, stream>>>(cb, ws);
    // zq = first TOTALc floats of out (same layout all rounds).
    vq_main<<<Mc / 256, 512, 0, stream>>>(z, cb, ws + ACC_FLOATS, ws, out,
                                          ema_cs, ema_w, out);
}

// Round 7
// 119.401 us; speedup vs baseline: 2.0265x; 2.0265x over previous
//
#include <hip/hip_runtime.h>

// VQ-VAE forward + EMA update, MI355X.
// Sizes fixed by the reference: B=64, C=D=8, H=W=64, K=512.
constexpr int Kc   = 512;
constexpr int Dc   = 8;
constexpr int HWc  = 4096;            // 64*64
constexpr int CHWc = Dc * HWc;        // 32768
constexpr int Mc   = 64 * HWc;        // 262144 vectors
constexpr int TOTALc = Mc * Dc;       // 2097152 elements of z / z_q

// 8 replica accumulators (one per XCD via blockIdx&7) to cut atomic contention.
constexpr int REP      = 8;
constexpr int RSTRIDE  = 4616;        // 512 counts + 4096 sums + 1 loss + 7 pad
constexpr int ACC_FLOATS = REP * RSTRIDE;   // 36928 floats (~148 KB)
// d_ws float layout:
//   [0 .. ACC_FLOATS)            replica accumulators (counts | sums | loss | pad) x8
//   [ACC_FLOATS .. +512)         e_sq[k]

typedef float v2f __attribute__((ext_vector_type(2)));

__global__ __launch_bounds__(256) void vq_prep(const float* __restrict__ cb,
                                               float* __restrict__ ws) {
    const int tid = blockIdx.x * 256 + threadIdx.x;
    float4* w4 = (float4*)ws;
    for (int i = tid; i < ACC_FLOATS / 4; i += gridDim.x * 256)
        w4[i] = float4{0.f, 0.f, 0.f, 0.f};
    if (blockIdx.x == 0) {
        for (int k = threadIdx.x; k < Kc; k += 256) {
            float s = 0.f;
#pragma unroll
            for (int c = 0; c < Dc; ++c) {
                const float e = cb[k * Dc + c];
                s = fmaf(e, e, s);
            }
            ws[ACC_FLOATS + k] = s;
        }
    }
}

// 1024 blocks x 512 threads; block owns 256 consecutive vectors.
// 8 k-groups x 1 wave; lane l scores V=4 vectors (l,l+64,l+128,l+192) via
// v_pk_fma_f32. KEY CHANGE vs the 46us r4 kernel: the k-loop reads the
// codebook + esq from LDS (staged once per block), not SMEM. Rationale:
// the 18 KB working set overflows the scalar cache -> chronic K$ misses +
// coarse out-of-order lgkmcnt drains pinned VALUBusy at ~58%. DS returns
// IN-ORDER (fine-grained counted waits; r2's regression was DS+SMEM mixing,
// not DS itself) and the loop now has zero SMEM/SGPR data operands.
// The staging region (18 KB) is reused as counts+sums after the k-loop, so
// LDS stays ~35 KB -> 4 blocks/CU. Accumulator init is free: ds_read_b64 at
// esq[k] puts ev in the LO half and op_sel_hi:[1,0,0] broadcasts src2's lo
// (hi half never read). Math BIT-IDENTICAL to r0/r4: a = esq[k];
// a += zz[c]*e[c], c ascending; strict-< first-index-wins; groups ascending.
__global__ __launch_bounds__(512, 8) void vq_main(const float* __restrict__ z,
                                                  const float* __restrict__ cb,
                                                  const float* __restrict__ esq,
                                                  float* __restrict__ ws,
                                                  float* __restrict__ zq) {
    // Region A: [0..4096) staged codebook, [4096..4608) staged esq, +4 pad
    // (b64 read at k=511 touches index 4608). After the k-loop it is
    // re-zeroed and reused as counts [0..512) + sums [512..4608).
    __shared__ float s_A[4612];            // 18.0 KB
    __shared__ float s_mn[8][256];         // 8 KB
    __shared__ int   s_im[8][256];         // 8 KB
    __shared__ float s_loss;

    const int t = threadIdx.x;

    // ---- stage codebook + esq into LDS (coalesced) ----
    {
        const float4* cb4 = (const float4*)cb;
        float4* A4 = (float4*)s_A;
        A4[t]       = cb4[t];              // floats [0 .. 2048)
        A4[t + 512] = cb4[t + 512];        // floats [2048 .. 4096)
        s_A[4096 + t] = esq[t];            // esq
    }

    const int l = t & 63;
    const int g  = __builtin_amdgcn_readfirstlane(t >> 6);   // 0..7
    const int k0 = g << 6;

    const int base = blockIdx.x * 256;        // 256-aligned -> one batch idx
    const int b  = base >> 12;
    const int n0 = (base & (HWc - 1)) + l;    // +64*j below never wraps 4096
    const float* zb = z + b * CHWc + n0;

    // zzA[c] = (-2*z[vec l][c], -2*z[vec l+64][c]); zzB: vecs l+128, l+192.
    v2f zzA[Dc], zzB[Dc];
#pragma unroll
    for (int c = 0; c < Dc; ++c) {
        zzA[c] = v2f{-2.0f * zb[c * HWc],       -2.0f * zb[c * HWc + 64]};
        zzB[c] = v2f{-2.0f * zb[c * HWc + 128], -2.0f * zb[c * HWc + 192]};
    }

    __syncthreads();   // staging complete

    const v2f* cbv = (const v2f*)s_A;         // 4 pairs per codebook row

    float mn0 = 3.4e38f, mn1 = 3.4e38f, mn2 = 3.4e38f, mn3 = 3.4e38f;
    int   i0 = k0, i1 = k0, i2 = k0, i3 = k0;
#pragma unroll 2
    for (int kk = 0; kk < 64; ++kk) {
        const int k = k0 + kk;
        // uniform addresses -> broadcast ds_read, conflict-free
        const v2f e01 = cbv[4 * k + 0];       // (e0,e1)
        const v2f e23 = cbv[4 * k + 1];       // (e2,e3)
        const v2f e45 = cbv[4 * k + 2];       // (e4,e5)
        const v2f e67 = cbv[4 * k + 3];       // (e6,e7)
        const v2f evv = *(const v2f*)&s_A[4096 + k];  // lo = esq[k], hi unused
        v2f aA, aB;
        // op_sel_hi:[1,0,0]: src1 lo-broadcast (e[2p]), src2 lo-broadcast
        // (ev into both halves; hi half of evv never read).
        // op_sel:[0,1,0] (default op_sel_hi [1,1,1]): src1 hi-broadcast
        // (e[2p+1]). Chain per acc: c ascending -> exact r0/r4 order.
        asm("v_pk_fma_f32 %0, %2, %4, %5 op_sel_hi:[1,0,0]\n\t"
            "v_pk_fma_f32 %1, %3, %4, %5 op_sel_hi:[1,0,0]\n\t"
            "v_pk_fma_f32 %0, %6, %4, %0 op_sel:[0,1,0]\n\t"
            "v_pk_fma_f32 %1, %7, %4, %1 op_sel:[0,1,0]"
            : "=&v"(aA), "=&v"(aB)
            : "v"(zzA[0]), "v"(zzB[0]), "v"(e01), "v"(evv),
              "v"(zzA[1]), "v"(zzB[1]));
#define PKSTEP(E, P0, P1)                                              \
        asm("v_pk_fma_f32 %0, %2, %4, %0 op_sel_hi:[1,0,1]\n\t"        \
            "v_pk_fma_f32 %1, %3, %4, %1 op_sel_hi:[1,0,1]\n\t"        \
            "v_pk_fma_f32 %0, %5, %4, %0 op_sel:[0,1,0]\n\t"           \
            "v_pk_fma_f32 %1, %6, %4, %1 op_sel:[0,1,0]"               \
            : "+v"(aA), "+v"(aB)                                       \
            : "v"(zzA[P0]), "v"(zzB[P0]), "v"(E), "v"(zzA[P1]), "v"(zzB[P1]))
        PKSTEP(e23, 2, 3);
        PKSTEP(e45, 4, 5);
        PKSTEP(e67, 6, 7);
#undef PKSTEP
        const float a0 = aA.x, a1 = aA.y, a2 = aB.x, a3 = aB.y;
        bool c;
        c = a0 < mn0; mn0 = c ? a0 : mn0; i0 = c ? k : i0;
        c = a1 < mn1; mn1 = c ? a1 : mn1; i1 = c ? k : i1;
        c = a2 < mn2; mn2 = c ? a2 : mn2; i2 = c ? k : i2;
        c = a3 < mn3; mn3 = c ? a3 : mn3; i3 = c ? k : i3;
    }
    s_mn[g][l]       = mn0;  s_im[g][l]       = i0;
    s_mn[g][l +  64] = mn1;  s_im[g][l +  64] = i1;
    s_mn[g][l + 128] = mn2;  s_im[g][l + 128] = i2;
    s_mn[g][l + 192] = mn3;  s_im[g][l + 192] = i3;
    __syncthreads();   // k-loop done; region A free for reuse

    // re-zero region A as counts [0..512) + sums [512..4608)
    for (int i = t; i < 4608; i += 512) s_A[i] = 0.f;
    if (t == 0) s_loss = 0.f;
    __syncthreads();

    if (t < 256) {
        const int v = t;                      // block-local vector id
        float mn = s_mn[0][v];
        int   im = s_im[0][v];
#pragma unroll
        for (int gg = 1; gg < 8; ++gg) {
            const float m2 = s_mn[gg][v];     // groups ascending in k:
            const int   j2 = s_im[gg][v];     // strict < keeps first index
            const bool  c2 = m2 < mn;
            mn = c2 ? m2 : mn;
            im = c2 ? j2 : im;
        }

        // Gather old-codebook row (16 KB table, L1-hot; 32B/lane).
        const float4* cb4 = (const float4*)cb;
        const float4 qa = cb4[im * 2], qb = cb4[im * 2 + 1];
        const float q[Dc] = {qa.x, qa.y, qa.z, qa.w, qb.x, qb.y, qb.z, qb.w};

        const int nv = (base & (HWc - 1)) + v;
        const float* zv = z + b * CHWc + nv;  // re-read z (L1/L2-hot)
        float* zqv = zq + b * CHWc + nv;
        float lsum = 0.f;
        float zr[Dc];
#pragma unroll
        for (int c = 0; c < Dc; ++c) {
            zr[c] = zv[c * HWc];
            zqv[c * HWc] = q[c];              // coalesced stores
            const float d = q[c] - zr[c];
            lsum = fmaf(d, d, lsum);
        }

        // Per-block LDS histogram (ds_add_f32) — coalesces same-index hits.
        unsafeAtomicAdd(&s_A[im], 1.0f);                 // counts
#pragma unroll
        for (int c = 0; c < Dc; ++c)
            unsafeAtomicAdd(&s_A[512 + im * Dc + c], zr[c]);  // sums
        unsafeAtomicAdd(&s_loss, lsum);
    }
    __syncthreads();

    // Flush non-zero bins to this block's replica accumulator (all 512 thr).
    float* acc = ws + (blockIdx.x & (REP - 1)) * RSTRIDE;
    for (int i = t; i < Kc; i += 512) {
        const float val = s_A[i];
        if (val != 0.f) unsafeAtomicAdd(&acc[i], val);
    }
    for (int i = t; i < Kc * Dc; i += 512) {
        const float val = s_A[512 + i];
        if (val != 0.f) unsafeAtomicAdd(&acc[512 + i], val);
    }
    if (t == 0) unsafeAtomicAdd(&acc[4608], s_loss);
}

// 9 blocks: every block redundantly recomputes the (cheap) counts/cs phase;
// block 0 writes cs + loss, blocks 1..8 each handle 512 of the 4096 K*D
// elements.
__global__ __launch_bounds__(512) void vq_final(const float* __restrict__ ws,
                                                const float* __restrict__ ema_cs,
                                                const float* __restrict__ ema_w,
                                                float* __restrict__ out) {
    constexpr float DEC  = 0.99f;
    constexpr float OMD  = (float)(1.0 - 0.99);      // matches jnp f32 cast
    constexpr float EPSf = 1e-5f;
    constexpr float KEPS = (float)(512 * 1e-5);      // 0.00512
    __shared__ float red[512];
    __shared__ float s_cs[512];

    const int t = threadIdx.x;
    // counts: lane-consecutive reads per replica (coalesced)
    float cnt = 0.f;
#pragma unroll
    for (int r = 0; r < REP; ++r) cnt += ws[r * RSTRIDE + t];
    const float ncs = ema_cs[t] * DEC + cnt * OMD;
    red[t] = ncs;
    __syncthreads();
    for (int s = 256; s > 0; s >>= 1) {
        if (t < s) red[t] += red[t + s];
        __syncthreads();
    }
    const float n  = red[0];
    const float cs = (ncs + EPSf) / (n + KEPS) * n;
    s_cs[t] = cs;

    float* out_loss = out + TOTALc;          // [1]
    float* out_cb   = out + TOTALc + 1;      // [K*D]
    float* out_cs   = out_cb + Kc * Dc;      // [K]
    float* out_nw   = out_cs + Kc;           // [K*D]

    __syncthreads();

    const int blk = blockIdx.x;
    if (blk == 0) {
        out_cs[t] = cs;
        if (t == 0) {
            float ls = 0.f;
#pragma unroll
            for (int r = 0; r < REP; ++r) ls += ws[r * RSTRIDE + 4608];
            out_loss[0] = ls * (1.0f / 2097152.0f);  // /2^21 exact
        }
    } else {
        const int e = (blk - 1) * 512 + t;   // one element per thread
        float sm = 0.f;
#pragma unroll
        for (int r = 0; r < REP; ++r) sm += ws[r * RSTRIDE + 512 + e];
        const float nw = ema_w[e] * DEC + sm * OMD;
        out_nw[e] = nw;
        out_cb[e] = nw / s_cs[e >> 3];
    }
}

extern "C" void kernel_launch(void* const* d_in, const int* in_sizes, int n_in,
                              void* d_out, int out_size, void* d_ws, size_t ws_size,
                              hipStream_t stream) {
    const float* z      = (const float*)d_in[0];
    const float* cb     = (const float*)d_in[1];
    const float* ema_cs = (const float*)d_in[2];
    const float* ema_w  = (const float*)d_in[3];
    float* out = (float*)d_out;
    float* ws  = (float*)d_ws;

    vq_prep<<<32, 256, 0, stream>>>(cb, ws);
    vq_main<<<Mc / 256, 512, 0, stream>>>(z, cb, ws + ACC_FLOATS, ws, out);
    vq_final<<<9, 512, 0, stream>>>(ws, ema_cs, ema_w, out);
}

// Round 8
// 109.499 us; speedup vs baseline: 2.2097x; 1.0904x over previous
//
#include <hip/hip_runtime.h>

// VQ-VAE forward + EMA update, MI355X.
// Sizes fixed by the reference: B=64, C=D=8, H=W=64, K=512.
constexpr int Kc   = 512;
constexpr int Dc   = 8;
constexpr int HWc  = 4096;            // 64*64
constexpr int CHWc = Dc * HWc;        // 32768
constexpr int Mc   = 64 * HWc;        // 262144 vectors
constexpr int TOTALc = Mc * Dc;       // 2097152 elements of z / z_q

// 8 replica accumulators (one per XCD via blockIdx&7) to cut atomic contention.
constexpr int REP      = 8;
constexpr int RSTRIDE  = 4616;        // 512 counts + 4096 sums + 1 loss + 7 pad
constexpr int ACC_FLOATS = REP * RSTRIDE;   // 36928 floats (~148 KB)
// d_ws float layout:
//   [0 .. ACC_FLOATS)            replica accumulators (counts | sums | loss | pad) x8
//   [ACC_FLOATS .. +512)         e_sq[k]

typedef float v2f __attribute__((ext_vector_type(2)));
typedef float f4  __attribute__((ext_vector_type(4)));
typedef unsigned long long ull;
typedef ull  u64x4 __attribute__((ext_vector_type(4)));

__global__ __launch_bounds__(256) void vq_prep(const float* __restrict__ cb,
                                               float* __restrict__ ws) {
    const int tid = blockIdx.x * 256 + threadIdx.x;
    float4* w4 = (float4*)ws;
    for (int i = tid; i < ACC_FLOATS / 4; i += gridDim.x * 256)
        w4[i] = float4{0.f, 0.f, 0.f, 0.f};
    if (blockIdx.x == 0) {
        for (int k = threadIdx.x; k < Kc; k += 256) {
            float s = 0.f;
#pragma unroll
            for (int c = 0; c < Dc; ++c) {
                const float e = cb[k * Dc + c];
                s = fmaf(e, e, s);
            }
            ws[ACC_FLOATS + k] = s;
        }
    }
}

// 1024 blocks x 512 threads; block owns 256 consecutive vectors.
// 8 k-groups x 1 wave; lane l scores V=4 vectors (l,l+64,l+128,l+192) via
// v_pk_fma_f32 (codebook pair in SGPR pair, lo/hi broadcast via op_sel).
// KEY CHANGE vs the 46us r4 kernel: SMEM REQUEST COUNT per code cut 5 -> 1.25.
// Model: K$ services ~1 scalar request/cyc/CU; r4's 5 requests/code/wave x
// 32 waves per ~92-cyc compute window = 1.7 req/cyc demand -> waves throttle
// to 92/160 = 57.5% busy (measured 58-59%, also explains r0==r4). Now each
// codebook row is ONE s_load_dwordx8 (u64x4 scalar load; sub-register pair
// extraction is free) and esq is ONE s_load_dwordx4 per 4 codes ->
// demand 0.43 req/cyc < 1. Math BIT-IDENTICAL to r0/r4: a = esq[k];
// a += zz[c]*e[c], c ascending; strict-< first-index-wins; groups ascending.
__global__ __launch_bounds__(512, 8) void vq_main(const float* __restrict__ z,
                                                  const float* __restrict__ cb,
                                                  const float* __restrict__ esq,
                                                  float* __restrict__ ws,
                                                  float* __restrict__ zq) {
    __shared__ float s_mn[8][256];         // 8 KB
    __shared__ int   s_im[8][256];         // 8 KB
    __shared__ float s_counts[Kc];         // 2 KB
    __shared__ float s_sums[Kc * Dc];      // 16 KB
    __shared__ float s_loss;

    const int t = threadIdx.x;
    for (int i = t; i < Kc; i += 512) s_counts[i] = 0.f;
    for (int i = t; i < Kc * Dc; i += 512) s_sums[i] = 0.f;
    if (t == 0) s_loss = 0.f;

    const int l = t & 63;
    // wave-uniform k-group; readfirstlane keeps codebook indices provably
    // uniform -> s_load (scalar) path for cb/esq.
    const int g  = __builtin_amdgcn_readfirstlane(t >> 6);   // 0..7
    const int k0 = g << 6;

    const int base = blockIdx.x * 256;        // 256-aligned -> one batch idx
    const int b  = base >> 12;
    const int n0 = (base & (HWc - 1)) + l;    // +64*j below never wraps 4096
    const float* zb = z + b * CHWc + n0;

    // zzA[c] = (-2*z[vec l][c], -2*z[vec l+64][c]); zzB: vecs l+128, l+192.
    v2f zzA[Dc], zzB[Dc];
#pragma unroll
    for (int c = 0; c < Dc; ++c) {
        zzA[c] = v2f{-2.0f * zb[c * HWc],       -2.0f * zb[c * HWc + 64]};
        zzB[c] = v2f{-2.0f * zb[c * HWc + 128], -2.0f * zb[c * HWc + 192]};
    }

    float mn0 = 3.4e38f, mn1 = 3.4e38f, mn2 = 3.4e38f, mn3 = 3.4e38f;
    int   i0 = k0, i1 = k0, i2 = k0, i3 = k0;
    // outer loop: 4 codes per iteration; one dwordx4 (esq) + 4 dwordx8 (rows)
    for (int kq = 0; kq < 16; ++kq) {
        const int kb = k0 + kq * 4;
        const f4 ev4 = *(const f4*)(esq + kb);           // s_load_dwordx4
#pragma unroll
        for (int j = 0; j < 4; ++j) {
            const int k = kb + j;
            const u64x4 row = *(const u64x4*)(cb + 8 * k);  // s_load_dwordx8
            const ull q0 = row.x, q1 = row.y, q2 = row.z, q3 = row.w;
            const float ev = ev4[j];
            const v2f vev2 = {ev, ev};
            v2f aA, aB;
            // op_sel_hi:[1,0,1] broadcasts the LOW dword of the sgpr pair
            // (e[2p]); op_sel:[0,1,0] (default op_sel_hi) broadcasts the
            // HIGH dword (e[2p+1]). First step folds the {ev,ev} addend
            // directly (same value & rounding as init-then-fma).
            asm("v_pk_fma_f32 %0, %2, %4, %5 op_sel_hi:[1,0,1]\n\t"
                "v_pk_fma_f32 %1, %3, %4, %5 op_sel_hi:[1,0,1]\n\t"
                "v_pk_fma_f32 %0, %6, %4, %0 op_sel:[0,1,0]\n\t"
                "v_pk_fma_f32 %1, %7, %4, %1 op_sel:[0,1,0]"
                : "=&v"(aA), "=&v"(aB)
                : "v"(zzA[0]), "v"(zzB[0]), "s"(q0), "v"(vev2),
                  "v"(zzA[1]), "v"(zzB[1]));
#define PKSTEP(Q, P0, P1)                                              \
            asm("v_pk_fma_f32 %0, %2, %4, %0 op_sel_hi:[1,0,1]\n\t"    \
                "v_pk_fma_f32 %1, %3, %4, %1 op_sel_hi:[1,0,1]\n\t"    \
                "v_pk_fma_f32 %0, %5, %4, %0 op_sel:[0,1,0]\n\t"       \
                "v_pk_fma_f32 %1, %6, %4, %1 op_sel:[0,1,0]"           \
                : "+v"(aA), "+v"(aB)                                   \
                : "v"(zzA[P0]), "v"(zzB[P0]), "s"(Q), "v"(zzA[P1]), "v"(zzB[P1]))
            PKSTEP(q1, 2, 3);
            PKSTEP(q2, 4, 5);
            PKSTEP(q3, 6, 7);
#undef PKSTEP
            const float a0 = aA.x, a1 = aA.y, a2 = aB.x, a3 = aB.y;
            bool c;
            c = a0 < mn0; mn0 = c ? a0 : mn0; i0 = c ? k : i0;
            c = a1 < mn1; mn1 = c ? a1 : mn1; i1 = c ? k : i1;
            c = a2 < mn2; mn2 = c ? a2 : mn2; i2 = c ? k : i2;
            c = a3 < mn3; mn3 = c ? a3 : mn3; i3 = c ? k : i3;
        }
    }
    s_mn[g][l]       = mn0;  s_im[g][l]       = i0;
    s_mn[g][l +  64] = mn1;  s_im[g][l +  64] = i1;
    s_mn[g][l + 128] = mn2;  s_im[g][l + 128] = i2;
    s_mn[g][l + 192] = mn3;  s_im[g][l + 192] = i3;
    __syncthreads();

    if (t < 256) {
        const int v = t;                      // block-local vector id
        float mn = s_mn[0][v];
        int   im = s_im[0][v];
#pragma unroll
        for (int gg = 1; gg < 8; ++gg) {
            const float m2 = s_mn[gg][v];     // groups ascending in k:
            const int   j2 = s_im[gg][v];     // strict < keeps first index
            const bool  c2 = m2 < mn;
            mn = c2 ? m2 : mn;
            im = c2 ? j2 : im;
        }

        // Gather old-codebook row (16 KB table, L1-hot; 32B/lane).
        const float4* cb4 = (const float4*)cb;
        const float4 qa = cb4[im * 2], qb = cb4[im * 2 + 1];
        const float q[Dc] = {qa.x, qa.y, qa.z, qa.w, qb.x, qb.y, qb.z, qb.w};

        const int nv = (base & (HWc - 1)) + v;
        const float* zv = z + b * CHWc + nv;  // re-read z (L1/L2-hot)
        float* zqv = zq + b * CHWc + nv;
        float lsum = 0.f;
        float zr[Dc];
#pragma unroll
        for (int c = 0; c < Dc; ++c) {
            zr[c] = zv[c * HWc];
            zqv[c * HWc] = q[c];              // coalesced stores
            const float d = q[c] - zr[c];
            lsum = fmaf(d, d, lsum);
        }

        // Per-block LDS histogram (ds_add_f32) — coalesces same-index hits.
        unsafeAtomicAdd(&s_counts[im], 1.0f);
#pragma unroll
        for (int c = 0; c < Dc; ++c)
            unsafeAtomicAdd(&s_sums[im * Dc + c], zr[c]);
        unsafeAtomicAdd(&s_loss, lsum);
    }
    __syncthreads();

    // Flush non-zero bins to this block's replica accumulator (all 512 thr).
    float* acc = ws + (blockIdx.x & (REP - 1)) * RSTRIDE;
    for (int i = t; i < Kc; i += 512) {
        const float val = s_counts[i];
        if (val != 0.f) unsafeAtomicAdd(&acc[i], val);
    }
    for (int i = t; i < Kc * Dc; i += 512) {
        const float val = s_sums[i];
        if (val != 0.f) unsafeAtomicAdd(&acc[512 + i], val);
    }
    if (t == 0) unsafeAtomicAdd(&acc[4608], s_loss);
}

// 9 blocks: every block redundantly recomputes the (cheap) counts/cs phase;
// block 0 writes cs + loss, blocks 1..8 each handle 512 of the 4096 K*D
// elements.
__global__ __launch_bounds__(512) void vq_final(const float* __restrict__ ws,
                                                const float* __restrict__ ema_cs,
                                                const float* __restrict__ ema_w,
                                                float* __restrict__ out) {
    constexpr float DEC  = 0.99f;
    constexpr float OMD  = (float)(1.0 - 0.99);      // matches jnp f32 cast
    constexpr float EPSf = 1e-5f;
    constexpr float KEPS = (float)(512 * 1e-5);      // 0.00512
    __shared__ float red[512];
    __shared__ float s_cs[512];

    const int t = threadIdx.x;
    // counts: lane-consecutive reads per replica (coalesced)
    float cnt = 0.f;
#pragma unroll
    for (int r = 0; r < REP; ++r) cnt += ws[r * RSTRIDE + t];
    const float ncs = ema_cs[t] * DEC + cnt * OMD;
    red[t] = ncs;
    __syncthreads();
    for (int s = 256; s > 0; s >>= 1) {
        if (t < s) red[t] += red[t + s];
        __syncthreads();
    }
    const float n  = red[0];
    const float cs = (ncs + EPSf) / (n + KEPS) * n;
    s_cs[t] = cs;

    float* out_loss = out + TOTALc;          // [1]
    float* out_cb   = out + TOTALc + 1;      // [K*D]
    float* out_cs   = out_cb + Kc * Dc;      // [K]
    float* out_nw   = out_cs + Kc;           // [K*D]

    __syncthreads();

    const int blk = blockIdx.x;
    if (blk == 0) {
        out_cs[t] = cs;
        if (t == 0) {
            float ls = 0.f;
#pragma unroll
            for (int r = 0; r < REP; ++r) ls += ws[r * RSTRIDE + 4608];
            out_loss[0] = ls * (1.0f / 2097152.0f);  // /2^21 exact
        }
    } else {
        const int e = (blk - 1) * 512 + t;   // one element per thread
        float sm = 0.f;
#pragma unroll
        for (int r = 0; r < REP; ++r) sm += ws[r * RSTRIDE + 512 + e];
        const float nw = ema_w[e] * DEC + sm * OMD;
        out_nw[e] = nw;
        out_cb[e] = nw / s_cs[e >> 3];
    }
}

extern "C" void kernel_launch(void* const* d_in, const int* in_sizes, int n_in,
                              void* d_out, int out_size, void* d_ws, size_t ws_size,
                              hipStream_t stream) {
    const float* z      = (const float*)d_in[0];
    const float* cb     = (const float*)d_in[1];
    const float* ema_cs = (const float*)d_in[2];
    const float* ema_w  = (const float*)d_in[3];
    float* out = (float*)d_out;
    float* ws  = (float*)d_ws;

    vq_prep<<<32, 256, 0, stream>>>(cb, ws);
    vq_main<<<Mc / 256, 512, 0, stream>>>(z, cb, ws + ACC_FLOATS, ws, out);
    vq_final<<<9, 512, 0, stream>>>(ws, ema_cs, ema_w, out);
}